// Round 17
// baseline (409.353 us; speedup 1.0000x reference)
//
#include <hip/hip_runtime.h>
#include <hip/hip_bf16.h>

// GAT (3-layer, HEADS=4, HID=32, concat=False head-mean) + global mean pool + MLP.
// R17 = R16 with the scatter write-inflation fixed: NSCAT 512 -> 64 so per-
//     (block,bucket) runs are ~49 edges (~196B) instead of ~1 edge (4B) —
//     R15 measured 82MB writeback for 6.4MB of data; ~13x line inflation.
//     bucket_sort now stages the bucket in LDS and sorts IN PLACE (csr == tmp),
//     removing a 6.4MB round trip. Aggregate unchanged (89us gather wall).

#define HEADS 4
#define HID 32
#define F_HID 128   // HEADS*HID
#define NEG_SLOPE 0.2f
#define BSHIFT 5
#define MAXB 3328   // max buckets supported (n <= 106496)
#define CAP 768     // fixed bucket capacity (E[bucket]=512, +11 sigma)
#define NSCAT 64    // scatter blocks: runs ~= E/NSCAT/nb ~= 49 edges ~= 196B

typedef float v2f __attribute__((ext_vector_type(2)));
using s8bf  = __attribute__((ext_vector_type(8))) short;   // 8 bf16 (4 VGPRs)
using f32x4 = __attribute__((ext_vector_type(4))) float;   // MFMA acc

__device__ __forceinline__ float lrelu(float v) { return v > 0.f ? v : NEG_SLOPE * v; }

__device__ __forceinline__ uint32_t bf16_rne(float f) {
    union { float f; uint32_t u; } c; c.f = f;
    return (c.u + 0x7fffu + ((c.u >> 16) & 1u)) >> 16;
}
__device__ __forceinline__ v2f up2(uint32_t u) {
    v2f r;
    r.x = __uint_as_float(u << 16);
    r.y = __uint_as_float(u & 0xffff0000u);
    return r;
}
__device__ __forceinline__ float bperm_f(int addr, float v) {
    return __int_as_float(__builtin_amdgcn_ds_bpermute(addr, __float_as_int(v)));
}
__device__ __forceinline__ int bperm_i(int addr, int v) {
    return __builtin_amdgcn_ds_bpermute(addr, v);
}
__device__ __forceinline__ v2f vshflxor(v2f v, int m) {
    v2f r; r.x = __shfl_xor(v.x, m); r.y = __shfl_xor(v.y, m); return r;
}

// ---------------- prep (all 3 layers) + gcursor seed + g zero ----------------

__device__ __forceinline__ void prep_one(const float* W, const float* a_s, const float* a_d,
                                         unsigned short* wbt, int FIN, int idx) {
    int LDK = FIN + 8;
    int r = idx / LDK, k = idx % LDK;
    float v = 0.f;
    if (k < FIN) {
        if (r < 128) {
            v = W[(size_t)k * F_HID + r];
        } else if (r < 136) {
            int j = r - 128;
            const float* av = (j < 4) ? a_s : a_d;
            int hd = j & 3;
            float s = 0.f;
            for (int c = 0; c < 32; c++)
                s += W[(size_t)k * F_HID + hd * 32 + c] * av[hd * 32 + c];
            v = s;
        }
    }
    wbt[idx] = (unsigned short)bf16_rne(v);
}

__global__ __launch_bounds__(256) void prep_all(const float* __restrict__ W1, const float* __restrict__ as1, const float* __restrict__ ad1,
                                                const float* __restrict__ W2, const float* __restrict__ as2, const float* __restrict__ ad2,
                                                const float* __restrict__ W3, const float* __restrict__ as3, const float* __restrict__ ad3,
                                                unsigned short* __restrict__ wbt1,
                                                unsigned short* __restrict__ wbt2,
                                                unsigned short* __restrict__ wbt3,
                                                int* __restrict__ gcursor, int nb,
                                                float* __restrict__ g) {
    int t = blockIdx.x * 256 + threadIdx.x;
    const int N1 = 144 * 136, N2 = 144 * 40, N3 = 144 * 40;
    if (t < N1) {
        prep_one(W1, as1, ad1, wbt1, 128, t);
    } else if (t < N1 + N2) {
        prep_one(W2, as2, ad2, wbt2, 32, t - N1);
    } else if (t < N1 + N2 + N3) {
        prep_one(W3, as3, ad3, wbt3, 32, t - N1 - N2);
    } else {
        int z = t - (N1 + N2 + N3);
        if (z < nb) gcursor[z] = z * CAP;            // fixed-capacity bucket seed
        else if (z < nb + 33) g[z - nb] = 0.f;       // g[0..31] sums, g[32] = counter
    }
}

// ---------------- fused: bucket_scatter (blocks 0..NSCAT-1) + gemm1 ----------------

__device__ void scatter_body(const int* __restrict__ ei, int E, int nb,
                             int* __restrict__ gcursor, uint32_t* __restrict__ tmp,
                             char* smem) {
    int* hist = (int*)smem;
    int* base = hist + MAXB;
    int t = threadIdx.x;
    int per = (E + NSCAT - 1) / NSCAT;
    int e0 = blockIdx.x * per;
    int e1 = e0 + per; if (e1 > E) e1 = E;

    for (int i = t; i < nb; i += 256) hist[i] = 0;
    __syncthreads();
    for (int i = e0 + t; i < e1; i += 256) {
        int d = ei[E + i];
        atomicAdd(&hist[d >> BSHIFT], 1);
    }
    __syncthreads();
    for (int i = t; i < nb; i += 256) {
        int c = hist[i];
        base[i] = c ? atomicAdd(&gcursor[i], c) : 0;
        hist[i] = 0;   // reuse as local cursor
    }
    __syncthreads();
    for (int i = e0 + t; i < e1; i += 256) {
        int d = ei[E + i];
        int s = ei[i];
        int b = d >> BSHIFT;
        int loc = atomicAdd(&hist[b], 1);
        tmp[base[b] + loc] = ((uint32_t)s << BSHIFT) | (uint32_t)(d & 31);
    }
}

// gemm body: xs in LDS; Wbt A-fragments read directly from global (L1/L2-resident).
template <int FIN>
__device__ void gemm_body(const float* __restrict__ x,
                          const unsigned short* __restrict__ wbt,
                          uint32_t* __restrict__ hb,
                          float* __restrict__ asrc,
                          float* __restrict__ adst, int n, int blk, char* smem) {
    constexpr int LDK = FIN + 8;
    constexpr int NPB = 64;
    unsigned short* xs = (unsigned short*)smem;
    int t = threadIdx.x;
    int base = blk * NPB;

    {   // stage x tile -> bf16 LDS
        constexpr int XIT = NPB * FIN / 4;
        for (int idx = t; idx < XIT; idx += 256) {
            int node = idx / (FIN / 4);
            int k4 = (idx % (FIN / 4)) * 4;
            int gnode = base + node;
            float4 v;
            if (gnode < n) v = *(const float4*)&x[(size_t)gnode * FIN + k4];
            else { v.x = 0.f; v.y = 0.f; v.z = 0.f; v.w = 0.f; }
            unsigned short* dst = &xs[node * LDK + k4];
            dst[0] = (unsigned short)bf16_rne(v.x);
            dst[1] = (unsigned short)bf16_rne(v.y);
            dst[2] = (unsigned short)bf16_rne(v.z);
            dst[3] = (unsigned short)bf16_rne(v.w);
        }
    }
    __syncthreads();

    int w = t >> 6;
    int l = t & 63;
    int lr = l & 15, lg = l >> 4;
    int node = base + w * 16 + lr;
    const unsigned short* xrow = &xs[(w * 16 + lr) * LDK + lg * 8];

    for (int ct = 0; ct < 9; ct++) {
        f32x4 acc = {0.f, 0.f, 0.f, 0.f};
        const unsigned short* arow = wbt + (ct * 16 + lr) * LDK + lg * 8;
#pragma unroll
        for (int kt = 0; kt < FIN / 32; kt++) {
            s8bf a = *(const s8bf*)(arow + kt * 32);   // global, L1/L2-hit
            s8bf b = *(const s8bf*)(xrow + kt * 32);   // LDS
            acc = __builtin_amdgcn_mfma_f32_16x16x32_bf16(a, b, acc, 0, 0, 0);
        }
        if (node < n) {
            if (ct < 8) {
                uint2 pp;
                pp.x = bf16_rne(acc[0]) | (bf16_rne(acc[1]) << 16);
                pp.y = bf16_rne(acc[2]) | (bf16_rne(acc[3]) << 16);
                *(uint2*)&hb[(size_t)node * 64 + ct * 8 + lg * 2] = pp;
            } else {
                float4 o; o.x = acc[0]; o.y = acc[1]; o.z = acc[2]; o.w = acc[3];
                if (lg == 0)      *(float4*)&asrc[node * 4] = o;
                else if (lg == 1) *(float4*)&adst[node * 4] = o;
            }
        }
    }
}

// fused front-end: blocks [0, NSCAT) scatter; blocks [NSCAT, ...) gemm1.
__global__ __launch_bounds__(256) void scatter_gemm1(const int* __restrict__ ei, int E, int nb,
                                                     int* __restrict__ gcursor,
                                                     uint32_t* __restrict__ tmp,
                                                     const float* __restrict__ x,
                                                     const unsigned short* __restrict__ wbt1,
                                                     uint32_t* __restrict__ hb,
                                                     float* __restrict__ asrc,
                                                     float* __restrict__ adst, int n) {
    __shared__ __align__(16) char smem[2 * MAXB * 4];
    if (blockIdx.x < NSCAT)
        scatter_body(ei, E, nb, gcursor, tmp, smem);
    else
        gemm_body<128>(x, wbt1, hb, asrc, adst, n, blockIdx.x - NSCAT, smem);
}

// standalone gemm for layers 2/3 (xs only: 64*40*2 = 5.1KB)
template <int FIN>
__global__ __launch_bounds__(256) void gemm_mfma(const float* __restrict__ x,
                                                 const unsigned short* __restrict__ wbt,
                                                 uint32_t* __restrict__ hb,
                                                 float* __restrict__ asrc,
                                                 float* __restrict__ adst, int n) {
    constexpr int LDK = FIN + 8;
    __shared__ __align__(16) char smem[64 * LDK * 2];
    gemm_body<FIN>(x, wbt, hb, asrc, adst, n, blockIdx.x, smem);
}

// per-bucket in-place sort: stage packed bucket in LDS, derive deg/row_start,
// write sorted srcs back over the SAME region (csr aliases tmp).
__global__ __launch_bounds__(256) void bucket_sort(uint32_t* __restrict__ tmp,
                                                   const int* __restrict__ gcursor,
                                                   int n,
                                                   int* __restrict__ row_start,
                                                   int* __restrict__ deg) {
    __shared__ uint32_t ebuf[CAP];
    __shared__ int cnt[32], pre[32];
    int b = blockIdx.x;
    int node0 = b << BSHIFT;
    int base = b * CAP;
    int cntE = gcursor[b] - base;
    int t = threadIdx.x;
    if (t < 32) cnt[t] = 0;
    __syncthreads();
    for (int i = t; i < cntE; i += 256) {
        uint32_t v = tmp[base + i];
        ebuf[i] = v;
        atomicAdd(&cnt[v & 31], 1);
    }
    __syncthreads();
    if (t == 0) {
        int run = 0;
        for (int i = 0; i < 32; i++) { pre[i] = run; run += cnt[i]; }
    }
    __syncthreads();
    if (t < 32) {
        int nd = node0 + t;
        if (nd < n) {
            row_start[nd] = base + pre[t];
            deg[nd] = cnt[t];
        }
        cnt[t] = pre[t];   // reuse as cursor
    }
    __syncthreads();
    for (int i = t; i < cntE; i += 256) {
        uint32_t v = ebuf[i];
        int pos = atomicAdd(&cnt[v & 31], 1);
        tmp[base + pos] = v >> BSHIFT;   // in-place: sorted src ids
    }
}

// Wave-per-node aggregate over bf16x2 h (256B rows), no online max. (unchanged)
__global__ __launch_bounds__(256) void aggregate(const uint32_t* __restrict__ hb,
                                                 const float* __restrict__ asrc,
                                                 const float* __restrict__ adst,
                                                 const int* __restrict__ row_start,
                                                 const int* __restrict__ deg,
                                                 const int* __restrict__ csr_src,
                                                 const float* __restrict__ bias,
                                                 float* __restrict__ xout, int n) {
    int d = blockIdx.x * 4 + (threadIdx.x >> 6);
    if (d >= n) return;
    int l = threadIdx.x & 63;
    int hd = l >> 4;                 // edge-phase head
    int ci = l & 15;                 // edge-phase edge slot
    int hh = (l & 15) >> 2;          // gather-phase head
    int permH = hh << 6;
    int permb = permH + (l >> 4) * 4;
    int rowoff = hh * 64 + (l & 3) * 16;

    int start = row_start[d];
    int cnt = deg[d];
    float ad = adst[d * HEADS + hd];
    float e_self = lrelu(asrc[d * HEADS + hd] + ad);
    const char* hbbase = (const char*)hb;

    uint4 us = *(const uint4*)(hbbase + (((uint32_t)d) << 8) + rowoff);

    float dsum = 0.f;
    v2f a0 = {0.f, 0.f}, a1 = {0.f, 0.f}, a2 = {0.f, 0.f}, a3 = {0.f, 0.f};
    const int* csr = csr_src + start;

#define ACC4(U, PJ)                         \
    {                                       \
        v2f p2 = {PJ, PJ};                  \
        a0 += p2 * up2((U).x);              \
        a1 += p2 * up2((U).y);              \
        a2 += p2 * up2((U).z);              \
        a3 += p2 * up2((U).w);              \
    }

    for (int j0 = 0; j0 < cnt; j0 += 32) {
        int ncnt = cnt - j0; if (ncnt > 32) ncnt = 32;
        int jA = j0 + ci;      if (jA > cnt - 1) jA = cnt - 1;
        int jB = j0 + 16 + ci; if (jB > cnt - 1) jB = cnt - 1;
        int s0 = csr[jA];
        int s1 = csr[jB];

        int sj0 = bperm_i(permb,      s0);
        int sj1 = bperm_i(permb + 16, s0);
        int sj2 = bperm_i(permb + 32, s0);
        int sj3 = bperm_i(permb + 48, s0);
        int sj4 = bperm_i(permb,      s1);
        int sj5 = bperm_i(permb + 16, s1);
        int sj6 = bperm_i(permb + 32, s1);
        int sj7 = bperm_i(permb + 48, s1);
        uint4 u0 = *(const uint4*)(hbbase + (((uint32_t)sj0) << 8) + rowoff);
        uint4 u1 = *(const uint4*)(hbbase + (((uint32_t)sj1) << 8) + rowoff);
        uint4 u2 = *(const uint4*)(hbbase + (((uint32_t)sj2) << 8) + rowoff);
        uint4 u3 = *(const uint4*)(hbbase + (((uint32_t)sj3) << 8) + rowoff);
        uint4 u4 = *(const uint4*)(hbbase + (((uint32_t)sj4) << 8) + rowoff);
        uint4 u5 = *(const uint4*)(hbbase + (((uint32_t)sj5) << 8) + rowoff);
        uint4 u6 = *(const uint4*)(hbbase + (((uint32_t)sj6) << 8) + rowoff);
        uint4 u7 = *(const uint4*)(hbbase + (((uint32_t)sj7) << 8) + rowoff);

        float pe0 = (ci < ncnt)      ? __expf(lrelu(asrc[s0 * HEADS + hd] + ad)) : 0.f;
        float pe1 = (ci + 16 < ncnt) ? __expf(lrelu(asrc[s1 * HEADS + hd] + ad)) : 0.f;
        dsum += pe0 + pe1;
        float pj0 = bperm_f(permb,      pe0);
        float pj1 = bperm_f(permb + 16, pe0);
        float pj2 = bperm_f(permb + 32, pe0);
        float pj3 = bperm_f(permb + 48, pe0);
        float pj4 = bperm_f(permb,      pe1);
        float pj5 = bperm_f(permb + 16, pe1);
        float pj6 = bperm_f(permb + 32, pe1);
        float pj7 = bperm_f(permb + 48, pe1);

        ACC4(u0, pj0); ACC4(u1, pj1); ACC4(u2, pj2); ACC4(u3, pj3);
        ACC4(u4, pj4); ACC4(u5, pj5); ACC4(u6, pj6); ACC4(u7, pj7);
    }
#undef ACC4

    dsum += __shfl_xor(dsum, 8);
    dsum += __shfl_xor(dsum, 4);
    dsum += __shfl_xor(dsum, 2);
    dsum += __shfl_xor(dsum, 1);
    float ps = __expf(e_self);
    float inv = 1.f / (dsum + ps + 1e-16f);
    float psg = bperm_f(permH, ps);
    float invg = bperm_f(permH, inv);

    a0 += vshflxor(a0, 16); a0 += vshflxor(a0, 32);
    a1 += vshflxor(a1, 16); a1 += vshflxor(a1, 32);
    a2 += vshflxor(a2, 16); a2 += vshflxor(a2, 32);
    a3 += vshflxor(a3, 16); a3 += vshflxor(a3, 32);

    v2f ps2 = {psg, psg};
    a0 += ps2 * up2(us.x);
    a1 += ps2 * up2(us.y);
    a2 += ps2 * up2(us.z);
    a3 += ps2 * up2(us.w);
    v2f iv2 = {invg, invg};
    a0 *= iv2; a1 *= iv2; a2 *= iv2; a3 *= iv2;

    a0 += vshflxor(a0, 4); a0 += vshflxor(a0, 8);
    a1 += vshflxor(a1, 4); a1 += vshflxor(a1, 8);
    a2 += vshflxor(a2, 4); a2 += vshflxor(a2, 8);
    a3 += vshflxor(a3, 4); a3 += vshflxor(a3, 8);

    if (l < 4) {
        const float4* bv = (const float4*)&bias[l * 8];
        float4 b0 = bv[0], b1 = bv[1];
        float4 o0, o1;
        o0.x = 0.25f * a0.x + b0.x; o0.y = 0.25f * a0.y + b0.y;
        o0.z = 0.25f * a1.x + b0.z; o0.w = 0.25f * a1.y + b0.w;
        o1.x = 0.25f * a2.x + b1.x; o1.y = 0.25f * a2.y + b1.y;
        o1.z = 0.25f * a3.x + b1.z; o1.w = 0.25f * a3.y + b1.w;
        o0.x = o0.x > 0.f ? o0.x : 0.f;  o0.y = o0.y > 0.f ? o0.y : 0.f;
        o0.z = o0.z > 0.f ? o0.z : 0.f;  o0.w = o0.w > 0.f ? o0.w : 0.f;
        o1.x = o1.x > 0.f ? o1.x : 0.f;  o1.y = o1.y > 0.f ? o1.y : 0.f;
        o1.z = o1.z > 0.f ? o1.z : 0.f;  o1.w = o1.w > 0.f ? o1.w : 0.f;
        float4* op = (float4*)&xout[(size_t)d * HID + l * 8];
        op[0] = o0;
        op[1] = o1;
    }
}

// ---------------- pooling + MLP (fused, last-block pattern) ----------------

__global__ __launch_bounds__(256) void pool_mlp(const float* __restrict__ x, int n,
                                                float* __restrict__ g,   // 32 sums + counter
                                                const float* __restrict__ lw1, const float* __restrict__ lb1,
                                                const float* __restrict__ lw2, const float* __restrict__ lb2,
                                                float* __restrict__ out, float invn) {
    __shared__ float sm[256];
    __shared__ int lastf;
    int t = threadIdx.x;
    int c = t & 31;
    int r = t >> 5;   // 8 node-rows per block
    float acc = 0.f;
    for (int i = blockIdx.x * 8 + r; i < n; i += gridDim.x * 8)
        acc += x[(size_t)i * HID + c];
    sm[t] = acc;
    __syncthreads();
    if (t < 32) {
        float v = 0.f;
#pragma unroll
        for (int k = 0; k < 8; k++) v += sm[t + 32 * k];
        atomicAdd(&g[t], v);
    }
    __threadfence();
    if (t == 0) {
        int old = atomicAdd((int*)&g[32], 1);
        lastf = (old == (int)gridDim.x - 1) ? 1 : 0;
    }
    __syncthreads();
    if (!lastf) return;
    __threadfence();
    if (t < 32) sm[t] = atomicAdd(&g[t], 0.f) * invn;
    __syncthreads();
    float q = 0.f;
    if (t < 16) {
        q = lb1[t];
        for (int cc = 0; cc < 32; cc++) q += sm[cc] * lw1[cc * 16 + t];
        q = q > 0.f ? q : 0.f;
        q *= lw2[t];
    }
    if (t < 64) {
#pragma unroll
        for (int off = 8; off >= 1; off >>= 1) q += __shfl_xor(q, off);
        if (t == 0) out[0] = q + lb2[0];
    }
}

// ---------------- launch ----------------

extern "C" void kernel_launch(void* const* d_in, const int* in_sizes, int n_in,
                              void* d_out, int out_size, void* d_ws, size_t ws_size,
                              hipStream_t stream) {
    const float* x   = (const float*)d_in[0];
    const int*   ei  = (const int*)d_in[1];
    const float* W1  = (const float*)d_in[2];
    const float* as1 = (const float*)d_in[3];
    const float* ad1 = (const float*)d_in[4];
    const float* b1  = (const float*)d_in[5];
    const float* W2  = (const float*)d_in[6];
    const float* as2 = (const float*)d_in[7];
    const float* ad2 = (const float*)d_in[8];
    const float* b2  = (const float*)d_in[9];
    const float* W3  = (const float*)d_in[10];
    const float* as3 = (const float*)d_in[11];
    const float* ad3 = (const float*)d_in[12];
    const float* b3  = (const float*)d_in[13];
    const float* lw1 = (const float*)d_in[14];
    const float* lb1 = (const float*)d_in[15];
    const float* lw2 = (const float*)d_in[16];
    const float* lb2 = (const float*)d_in[17];
    float* out = (float*)d_out;

    int n = in_sizes[0] / 128;   // 100000
    int E = in_sizes[1] / 2;     // 1600000
    int nb = (n + 31) >> BSHIFT; // 3125 buckets

    // workspace carve (256B aligned)
    char* p = (char*)d_ws;
    auto alloc = [&](size_t bytes) -> void* {
        void* r = (void*)p;
        p += (bytes + 255) & ~(size_t)255;
        return r;
    };
    int* deg       = (int*)alloc((size_t)n * 4);
    int* row_start = (int*)alloc((size_t)n * 4);
    int* gcursor   = (int*)alloc((size_t)nb * 4);
    uint32_t* tmp  = (uint32_t*)alloc((size_t)nb * CAP * 4);// padded; sorted in place -> csr
    float* asrc    = (float*)alloc((size_t)n * HEADS * 4);
    float* adst    = (float*)alloc((size_t)n * HEADS * 4);
    uint32_t* hb   = (uint32_t*)alloc((size_t)n * 64 * 4);  // bf16x2 packed h (256B rows)
    float* xA      = (float*)alloc((size_t)n * HID * 4);
    float* xB      = (float*)alloc((size_t)n * HID * 4);
    float* g       = (float*)alloc(33 * 4);                 // 32 sums + arrival counter
    unsigned short* wbt1 = (unsigned short*)alloc((size_t)144 * 136 * 2);
    unsigned short* wbt2 = (unsigned short*)alloc((size_t)144 * 40 * 2);
    unsigned short* wbt3 = (unsigned short*)alloc((size_t)144 * 40 * 2);

    // prep all weights + seed gcursor + zero g (one dispatch)
    int prep_tot = 144 * 136 + 2 * 144 * 40 + nb + 33;
    prep_all<<<(prep_tot + 255) / 256, 256, 0, stream>>>(
        W1, as1, ad1, W2, as2, ad2, W3, as3, ad3,
        wbt1, wbt2, wbt3, gcursor, nb, g);

    int gb = (n + 63) / 64;
    int ggb = (n + 3) / 4;

    // fused: bucket scatter (64 blocks) + layer-1 gemm (one dispatch)
    scatter_gemm1<<<NSCAT + gb, 256, 0, stream>>>(ei, E, nb, gcursor, tmp,
                                                  x, wbt1, hb, asrc, adst, n);
    bucket_sort<<<nb, 256, 0, stream>>>(tmp, gcursor, n, row_start, deg);
    int* csr = (int*)tmp;   // sorted in place

    // layer 1 aggregate
    aggregate<<<ggb, 256, 0, stream>>>(hb, asrc, adst, row_start, deg, csr, b1, xA, n);

    // layer 2
    gemm_mfma<32><<<gb, 256, 0, stream>>>(xA, wbt2, hb, asrc, adst, n);
    aggregate<<<ggb, 256, 0, stream>>>(hb, asrc, adst, row_start, deg, csr, b2, xB, n);

    // layer 3
    gemm_mfma<32><<<gb, 256, 0, stream>>>(xB, wbt3, hb, asrc, adst, n);
    aggregate<<<ggb, 256, 0, stream>>>(hb, asrc, adst, row_start, deg, csr, b3, xA, n);

    // pooling + MLP (fused; g/counter zeroed by prep_all each call)
    pool_mlp<<<256, 256, 0, stream>>>(xA, n, g, lw1, lb1, lw2, lb2, out, 1.0f / (float)n);
}

// Round 18
// 375.602 us; speedup vs baseline: 1.0899x; 1.0899x over previous
//
#include <hip/hip_runtime.h>
#include <hip/hip_bf16.h>

// GAT (3-layer, HEADS=4, HID=32, concat=False head-mean) + global mean pool + MLP.
// R18: NSCAT 64 -> 256 (R17's 64 blocks made the scatter the serial pole,
//     110-130us; 512 was <89us in R16; 256 = middle: 24 iter/block, half the
//     per-address atomic chains of 512). Keep R17's in-place LDS bucket_sort.
//     gemm x-staging: pack bf16 pairs -> uint2 (1x 8B ds_write vs 4 scalar).
//     Aggregate unchanged (89.5us random-gather transaction wall).

#define HEADS 4
#define HID 32
#define F_HID 128   // HEADS*HID
#define NEG_SLOPE 0.2f
#define BSHIFT 5
#define MAXB 3328   // max buckets supported (n <= 106496)
#define CAP 768     // fixed bucket capacity (E[bucket]=512, +11 sigma)
#define NSCAT 256   // scatter blocks

typedef float v2f __attribute__((ext_vector_type(2)));
using s8bf  = __attribute__((ext_vector_type(8))) short;   // 8 bf16 (4 VGPRs)
using f32x4 = __attribute__((ext_vector_type(4))) float;   // MFMA acc

__device__ __forceinline__ float lrelu(float v) { return v > 0.f ? v : NEG_SLOPE * v; }

__device__ __forceinline__ uint32_t bf16_rne(float f) {
    union { float f; uint32_t u; } c; c.f = f;
    return (c.u + 0x7fffu + ((c.u >> 16) & 1u)) >> 16;
}
__device__ __forceinline__ v2f up2(uint32_t u) {
    v2f r;
    r.x = __uint_as_float(u << 16);
    r.y = __uint_as_float(u & 0xffff0000u);
    return r;
}
__device__ __forceinline__ float bperm_f(int addr, float v) {
    return __int_as_float(__builtin_amdgcn_ds_bpermute(addr, __float_as_int(v)));
}
__device__ __forceinline__ int bperm_i(int addr, int v) {
    return __builtin_amdgcn_ds_bpermute(addr, v);
}
__device__ __forceinline__ v2f vshflxor(v2f v, int m) {
    v2f r; r.x = __shfl_xor(v.x, m); r.y = __shfl_xor(v.y, m); return r;
}

// ---------------- prep (all 3 layers) + gcursor seed + g zero ----------------

__device__ __forceinline__ void prep_one(const float* W, const float* a_s, const float* a_d,
                                         unsigned short* wbt, int FIN, int idx) {
    int LDK = FIN + 8;
    int r = idx / LDK, k = idx % LDK;
    float v = 0.f;
    if (k < FIN) {
        if (r < 128) {
            v = W[(size_t)k * F_HID + r];
        } else if (r < 136) {
            int j = r - 128;
            const float* av = (j < 4) ? a_s : a_d;
            int hd = j & 3;
            float s = 0.f;
            for (int c = 0; c < 32; c++)
                s += W[(size_t)k * F_HID + hd * 32 + c] * av[hd * 32 + c];
            v = s;
        }
    }
    wbt[idx] = (unsigned short)bf16_rne(v);
}

__global__ __launch_bounds__(256) void prep_all(const float* __restrict__ W1, const float* __restrict__ as1, const float* __restrict__ ad1,
                                                const float* __restrict__ W2, const float* __restrict__ as2, const float* __restrict__ ad2,
                                                const float* __restrict__ W3, const float* __restrict__ as3, const float* __restrict__ ad3,
                                                unsigned short* __restrict__ wbt1,
                                                unsigned short* __restrict__ wbt2,
                                                unsigned short* __restrict__ wbt3,
                                                int* __restrict__ gcursor, int nb,
                                                float* __restrict__ g) {
    int t = blockIdx.x * 256 + threadIdx.x;
    const int N1 = 144 * 136, N2 = 144 * 40, N3 = 144 * 40;
    if (t < N1) {
        prep_one(W1, as1, ad1, wbt1, 128, t);
    } else if (t < N1 + N2) {
        prep_one(W2, as2, ad2, wbt2, 32, t - N1);
    } else if (t < N1 + N2 + N3) {
        prep_one(W3, as3, ad3, wbt3, 32, t - N1 - N2);
    } else {
        int z = t - (N1 + N2 + N3);
        if (z < nb) gcursor[z] = z * CAP;            // fixed-capacity bucket seed
        else if (z < nb + 33) g[z - nb] = 0.f;       // g[0..31] sums, g[32] = counter
    }
}

// ---------------- fused: bucket_scatter (blocks 0..NSCAT-1) + gemm1 ----------------

__device__ void scatter_body(const int* __restrict__ ei, int E, int nb,
                             int* __restrict__ gcursor, uint32_t* __restrict__ tmp,
                             char* smem) {
    int* hist = (int*)smem;
    int* base = hist + MAXB;
    int t = threadIdx.x;
    int per = (E + NSCAT - 1) / NSCAT;
    int e0 = blockIdx.x * per;
    int e1 = e0 + per; if (e1 > E) e1 = E;

    for (int i = t; i < nb; i += 256) hist[i] = 0;
    __syncthreads();
    for (int i = e0 + t; i < e1; i += 256) {
        int d = ei[E + i];
        atomicAdd(&hist[d >> BSHIFT], 1);
    }
    __syncthreads();
    for (int i = t; i < nb; i += 256) {
        int c = hist[i];
        base[i] = c ? atomicAdd(&gcursor[i], c) : 0;
        hist[i] = 0;   // reuse as local cursor
    }
    __syncthreads();
    for (int i = e0 + t; i < e1; i += 256) {
        int d = ei[E + i];
        int s = ei[i];
        int b = d >> BSHIFT;
        int loc = atomicAdd(&hist[b], 1);
        tmp[base[b] + loc] = ((uint32_t)s << BSHIFT) | (uint32_t)(d & 31);
    }
}

// gemm body: xs in LDS; Wbt A-fragments read directly from global (L1/L2-resident).
template <int FIN>
__device__ void gemm_body(const float* __restrict__ x,
                          const unsigned short* __restrict__ wbt,
                          uint32_t* __restrict__ hb,
                          float* __restrict__ asrc,
                          float* __restrict__ adst, int n, int blk, char* smem) {
    constexpr int LDK = FIN + 8;
    constexpr int NPB = 64;
    unsigned short* xs = (unsigned short*)smem;
    int t = threadIdx.x;
    int base = blk * NPB;

    {   // stage x tile -> bf16 LDS (packed uint2 writes, 8B each)
        constexpr int XIT = NPB * FIN / 4;
        for (int idx = t; idx < XIT; idx += 256) {
            int node = idx / (FIN / 4);
            int k4 = (idx % (FIN / 4)) * 4;
            int gnode = base + node;
            float4 v;
            if (gnode < n) v = *(const float4*)&x[(size_t)gnode * FIN + k4];
            else { v.x = 0.f; v.y = 0.f; v.z = 0.f; v.w = 0.f; }
            uint2 pk;
            pk.x = bf16_rne(v.x) | (bf16_rne(v.y) << 16);
            pk.y = bf16_rne(v.z) | (bf16_rne(v.w) << 16);
            *(uint2*)&xs[node * LDK + k4] = pk;   // (node*LDK+k4) % 4 == 0 -> 8B aligned
        }
    }
    __syncthreads();

    int w = t >> 6;
    int l = t & 63;
    int lr = l & 15, lg = l >> 4;
    int node = base + w * 16 + lr;
    const unsigned short* xrow = &xs[(w * 16 + lr) * LDK + lg * 8];

    for (int ct = 0; ct < 9; ct++) {
        f32x4 acc = {0.f, 0.f, 0.f, 0.f};
        const unsigned short* arow = wbt + (ct * 16 + lr) * LDK + lg * 8;
#pragma unroll
        for (int kt = 0; kt < FIN / 32; kt++) {
            s8bf a = *(const s8bf*)(arow + kt * 32);   // global, L1/L2-hit
            s8bf b = *(const s8bf*)(xrow + kt * 32);   // LDS
            acc = __builtin_amdgcn_mfma_f32_16x16x32_bf16(a, b, acc, 0, 0, 0);
        }
        if (node < n) {
            if (ct < 8) {
                uint2 pp;
                pp.x = bf16_rne(acc[0]) | (bf16_rne(acc[1]) << 16);
                pp.y = bf16_rne(acc[2]) | (bf16_rne(acc[3]) << 16);
                *(uint2*)&hb[(size_t)node * 64 + ct * 8 + lg * 2] = pp;
            } else {
                float4 o; o.x = acc[0]; o.y = acc[1]; o.z = acc[2]; o.w = acc[3];
                if (lg == 0)      *(float4*)&asrc[node * 4] = o;
                else if (lg == 1) *(float4*)&adst[node * 4] = o;
            }
        }
    }
}

// fused front-end: blocks [0, NSCAT) scatter; blocks [NSCAT, ...) gemm1.
__global__ __launch_bounds__(256) void scatter_gemm1(const int* __restrict__ ei, int E, int nb,
                                                     int* __restrict__ gcursor,
                                                     uint32_t* __restrict__ tmp,
                                                     const float* __restrict__ x,
                                                     const unsigned short* __restrict__ wbt1,
                                                     uint32_t* __restrict__ hb,
                                                     float* __restrict__ asrc,
                                                     float* __restrict__ adst, int n) {
    __shared__ __align__(16) char smem[2 * MAXB * 4];
    if (blockIdx.x < NSCAT)
        scatter_body(ei, E, nb, gcursor, tmp, smem);
    else
        gemm_body<128>(x, wbt1, hb, asrc, adst, n, blockIdx.x - NSCAT, smem);
}

// standalone gemm for layers 2/3 (xs only: 64*40*2 = 5.1KB)
template <int FIN>
__global__ __launch_bounds__(256) void gemm_mfma(const float* __restrict__ x,
                                                 const unsigned short* __restrict__ wbt,
                                                 uint32_t* __restrict__ hb,
                                                 float* __restrict__ asrc,
                                                 float* __restrict__ adst, int n) {
    constexpr int LDK = FIN + 8;
    __shared__ __align__(16) char smem[64 * LDK * 2];
    gemm_body<FIN>(x, wbt, hb, asrc, adst, n, blockIdx.x, smem);
}

// per-bucket in-place sort: stage packed bucket in LDS, derive deg/row_start,
// write sorted srcs back over the SAME region (csr aliases tmp).
__global__ __launch_bounds__(256) void bucket_sort(uint32_t* __restrict__ tmp,
                                                   const int* __restrict__ gcursor,
                                                   int n,
                                                   int* __restrict__ row_start,
                                                   int* __restrict__ deg) {
    __shared__ uint32_t ebuf[CAP];
    __shared__ int cnt[32], pre[32];
    int b = blockIdx.x;
    int node0 = b << BSHIFT;
    int base = b * CAP;
    int cntE = gcursor[b] - base;
    int t = threadIdx.x;
    if (t < 32) cnt[t] = 0;
    __syncthreads();
    for (int i = t; i < cntE; i += 256) {
        uint32_t v = tmp[base + i];
        ebuf[i] = v;
        atomicAdd(&cnt[v & 31], 1);
    }
    __syncthreads();
    if (t == 0) {
        int run = 0;
        for (int i = 0; i < 32; i++) { pre[i] = run; run += cnt[i]; }
    }
    __syncthreads();
    if (t < 32) {
        int nd = node0 + t;
        if (nd < n) {
            row_start[nd] = base + pre[t];
            deg[nd] = cnt[t];
        }
        cnt[t] = pre[t];   // reuse as cursor
    }
    __syncthreads();
    for (int i = t; i < cntE; i += 256) {
        uint32_t v = ebuf[i];
        int pos = atomicAdd(&cnt[v & 31], 1);
        tmp[base + pos] = v >> BSHIFT;   // in-place: sorted src ids
    }
}

// Wave-per-node aggregate over bf16x2 h (256B rows), no online max. (unchanged)
__global__ __launch_bounds__(256) void aggregate(const uint32_t* __restrict__ hb,
                                                 const float* __restrict__ asrc,
                                                 const float* __restrict__ adst,
                                                 const int* __restrict__ row_start,
                                                 const int* __restrict__ deg,
                                                 const int* __restrict__ csr_src,
                                                 const float* __restrict__ bias,
                                                 float* __restrict__ xout, int n) {
    int d = blockIdx.x * 4 + (threadIdx.x >> 6);
    if (d >= n) return;
    int l = threadIdx.x & 63;
    int hd = l >> 4;                 // edge-phase head
    int ci = l & 15;                 // edge-phase edge slot
    int hh = (l & 15) >> 2;          // gather-phase head
    int permH = hh << 6;
    int permb = permH + (l >> 4) * 4;
    int rowoff = hh * 64 + (l & 3) * 16;

    int start = row_start[d];
    int cnt = deg[d];
    float ad = adst[d * HEADS + hd];
    float e_self = lrelu(asrc[d * HEADS + hd] + ad);
    const char* hbbase = (const char*)hb;

    uint4 us = *(const uint4*)(hbbase + (((uint32_t)d) << 8) + rowoff);

    float dsum = 0.f;
    v2f a0 = {0.f, 0.f}, a1 = {0.f, 0.f}, a2 = {0.f, 0.f}, a3 = {0.f, 0.f};
    const int* csr = csr_src + start;

#define ACC4(U, PJ)                         \
    {                                       \
        v2f p2 = {PJ, PJ};                  \
        a0 += p2 * up2((U).x);              \
        a1 += p2 * up2((U).y);              \
        a2 += p2 * up2((U).z);              \
        a3 += p2 * up2((U).w);              \
    }

    for (int j0 = 0; j0 < cnt; j0 += 32) {
        int ncnt = cnt - j0; if (ncnt > 32) ncnt = 32;
        int jA = j0 + ci;      if (jA > cnt - 1) jA = cnt - 1;
        int jB = j0 + 16 + ci; if (jB > cnt - 1) jB = cnt - 1;
        int s0 = csr[jA];
        int s1 = csr[jB];

        int sj0 = bperm_i(permb,      s0);
        int sj1 = bperm_i(permb + 16, s0);
        int sj2 = bperm_i(permb + 32, s0);
        int sj3 = bperm_i(permb + 48, s0);
        int sj4 = bperm_i(permb,      s1);
        int sj5 = bperm_i(permb + 16, s1);
        int sj6 = bperm_i(permb + 32, s1);
        int sj7 = bperm_i(permb + 48, s1);
        uint4 u0 = *(const uint4*)(hbbase + (((uint32_t)sj0) << 8) + rowoff);
        uint4 u1 = *(const uint4*)(hbbase + (((uint32_t)sj1) << 8) + rowoff);
        uint4 u2 = *(const uint4*)(hbbase + (((uint32_t)sj2) << 8) + rowoff);
        uint4 u3 = *(const uint4*)(hbbase + (((uint32_t)sj3) << 8) + rowoff);
        uint4 u4 = *(const uint4*)(hbbase + (((uint32_t)sj4) << 8) + rowoff);
        uint4 u5 = *(const uint4*)(hbbase + (((uint32_t)sj5) << 8) + rowoff);
        uint4 u6 = *(const uint4*)(hbbase + (((uint32_t)sj6) << 8) + rowoff);
        uint4 u7 = *(const uint4*)(hbbase + (((uint32_t)sj7) << 8) + rowoff);

        float pe0 = (ci < ncnt)      ? __expf(lrelu(asrc[s0 * HEADS + hd] + ad)) : 0.f;
        float pe1 = (ci + 16 < ncnt) ? __expf(lrelu(asrc[s1 * HEADS + hd] + ad)) : 0.f;
        dsum += pe0 + pe1;
        float pj0 = bperm_f(permb,      pe0);
        float pj1 = bperm_f(permb + 16, pe0);
        float pj2 = bperm_f(permb + 32, pe0);
        float pj3 = bperm_f(permb + 48, pe0);
        float pj4 = bperm_f(permb,      pe1);
        float pj5 = bperm_f(permb + 16, pe1);
        float pj6 = bperm_f(permb + 32, pe1);
        float pj7 = bperm_f(permb + 48, pe1);

        ACC4(u0, pj0); ACC4(u1, pj1); ACC4(u2, pj2); ACC4(u3, pj3);
        ACC4(u4, pj4); ACC4(u5, pj5); ACC4(u6, pj6); ACC4(u7, pj7);
    }
#undef ACC4

    dsum += __shfl_xor(dsum, 8);
    dsum += __shfl_xor(dsum, 4);
    dsum += __shfl_xor(dsum, 2);
    dsum += __shfl_xor(dsum, 1);
    float ps = __expf(e_self);
    float inv = 1.f / (dsum + ps + 1e-16f);
    float psg = bperm_f(permH, ps);
    float invg = bperm_f(permH, inv);

    a0 += vshflxor(a0, 16); a0 += vshflxor(a0, 32);
    a1 += vshflxor(a1, 16); a1 += vshflxor(a1, 32);
    a2 += vshflxor(a2, 16); a2 += vshflxor(a2, 32);
    a3 += vshflxor(a3, 16); a3 += vshflxor(a3, 32);

    v2f ps2 = {psg, psg};
    a0 += ps2 * up2(us.x);
    a1 += ps2 * up2(us.y);
    a2 += ps2 * up2(us.z);
    a3 += ps2 * up2(us.w);
    v2f iv2 = {invg, invg};
    a0 *= iv2; a1 *= iv2; a2 *= iv2; a3 *= iv2;

    a0 += vshflxor(a0, 4); a0 += vshflxor(a0, 8);
    a1 += vshflxor(a1, 4); a1 += vshflxor(a1, 8);
    a2 += vshflxor(a2, 4); a2 += vshflxor(a2, 8);
    a3 += vshflxor(a3, 4); a3 += vshflxor(a3, 8);

    if (l < 4) {
        const float4* bv = (const float4*)&bias[l * 8];
        float4 b0 = bv[0], b1 = bv[1];
        float4 o0, o1;
        o0.x = 0.25f * a0.x + b0.x; o0.y = 0.25f * a0.y + b0.y;
        o0.z = 0.25f * a1.x + b0.z; o0.w = 0.25f * a1.y + b0.w;
        o1.x = 0.25f * a2.x + b1.x; o1.y = 0.25f * a2.y + b1.y;
        o1.z = 0.25f * a3.x + b1.z; o1.w = 0.25f * a3.y + b1.w;
        o0.x = o0.x > 0.f ? o0.x : 0.f;  o0.y = o0.y > 0.f ? o0.y : 0.f;
        o0.z = o0.z > 0.f ? o0.z : 0.f;  o0.w = o0.w > 0.f ? o0.w : 0.f;
        o1.x = o1.x > 0.f ? o1.x : 0.f;  o1.y = o1.y > 0.f ? o1.y : 0.f;
        o1.z = o1.z > 0.f ? o1.z : 0.f;  o1.w = o1.w > 0.f ? o1.w : 0.f;
        float4* op = (float4*)&xout[(size_t)d * HID + l * 8];
        op[0] = o0;
        op[1] = o1;
    }
}

// ---------------- pooling + MLP (fused, last-block pattern) ----------------

__global__ __launch_bounds__(256) void pool_mlp(const float* __restrict__ x, int n,
                                                float* __restrict__ g,   // 32 sums + counter
                                                const float* __restrict__ lw1, const float* __restrict__ lb1,
                                                const float* __restrict__ lw2, const float* __restrict__ lb2,
                                                float* __restrict__ out, float invn) {
    __shared__ float sm[256];
    __shared__ int lastf;
    int t = threadIdx.x;
    int c = t & 31;
    int r = t >> 5;   // 8 node-rows per block
    float acc = 0.f;
    for (int i = blockIdx.x * 8 + r; i < n; i += gridDim.x * 8)
        acc += x[(size_t)i * HID + c];
    sm[t] = acc;
    __syncthreads();
    if (t < 32) {
        float v = 0.f;
#pragma unroll
        for (int k = 0; k < 8; k++) v += sm[t + 32 * k];
        atomicAdd(&g[t], v);
    }
    __threadfence();
    if (t == 0) {
        int old = atomicAdd((int*)&g[32], 1);
        lastf = (old == (int)gridDim.x - 1) ? 1 : 0;
    }
    __syncthreads();
    if (!lastf) return;
    __threadfence();
    if (t < 32) sm[t] = atomicAdd(&g[t], 0.f) * invn;
    __syncthreads();
    float q = 0.f;
    if (t < 16) {
        q = lb1[t];
        for (int cc = 0; cc < 32; cc++) q += sm[cc] * lw1[cc * 16 + t];
        q = q > 0.f ? q : 0.f;
        q *= lw2[t];
    }
    if (t < 64) {
#pragma unroll
        for (int off = 8; off >= 1; off >>= 1) q += __shfl_xor(q, off);
        if (t == 0) out[0] = q + lb2[0];
    }
}

// ---------------- launch ----------------

extern "C" void kernel_launch(void* const* d_in, const int* in_sizes, int n_in,
                              void* d_out, int out_size, void* d_ws, size_t ws_size,
                              hipStream_t stream) {
    const float* x   = (const float*)d_in[0];
    const int*   ei  = (const int*)d_in[1];
    const float* W1  = (const float*)d_in[2];
    const float* as1 = (const float*)d_in[3];
    const float* ad1 = (const float*)d_in[4];
    const float* b1  = (const float*)d_in[5];
    const float* W2  = (const float*)d_in[6];
    const float* as2 = (const float*)d_in[7];
    const float* ad2 = (const float*)d_in[8];
    const float* b2  = (const float*)d_in[9];
    const float* W3  = (const float*)d_in[10];
    const float* as3 = (const float*)d_in[11];
    const float* ad3 = (const float*)d_in[12];
    const float* b3  = (const float*)d_in[13];
    const float* lw1 = (const float*)d_in[14];
    const float* lb1 = (const float*)d_in[15];
    const float* lw2 = (const float*)d_in[16];
    const float* lb2 = (const float*)d_in[17];
    float* out = (float*)d_out;

    int n = in_sizes[0] / 128;   // 100000
    int E = in_sizes[1] / 2;     // 1600000
    int nb = (n + 31) >> BSHIFT; // 3125 buckets

    // workspace carve (256B aligned)
    char* p = (char*)d_ws;
    auto alloc = [&](size_t bytes) -> void* {
        void* r = (void*)p;
        p += (bytes + 255) & ~(size_t)255;
        return r;
    };
    int* deg       = (int*)alloc((size_t)n * 4);
    int* row_start = (int*)alloc((size_t)n * 4);
    int* gcursor   = (int*)alloc((size_t)nb * 4);
    uint32_t* tmp  = (uint32_t*)alloc((size_t)nb * CAP * 4);// padded; sorted in place -> csr
    float* asrc    = (float*)alloc((size_t)n * HEADS * 4);
    float* adst    = (float*)alloc((size_t)n * HEADS * 4);
    uint32_t* hb   = (uint32_t*)alloc((size_t)n * 64 * 4);  // bf16x2 packed h (256B rows)
    float* xA      = (float*)alloc((size_t)n * HID * 4);
    float* xB      = (float*)alloc((size_t)n * HID * 4);
    float* g       = (float*)alloc(33 * 4);                 // 32 sums + arrival counter
    unsigned short* wbt1 = (unsigned short*)alloc((size_t)144 * 136 * 2);
    unsigned short* wbt2 = (unsigned short*)alloc((size_t)144 * 40 * 2);
    unsigned short* wbt3 = (unsigned short*)alloc((size_t)144 * 40 * 2);

    // prep all weights + seed gcursor + zero g (one dispatch)
    int prep_tot = 144 * 136 + 2 * 144 * 40 + nb + 33;
    prep_all<<<(prep_tot + 255) / 256, 256, 0, stream>>>(
        W1, as1, ad1, W2, as2, ad2, W3, as3, ad3,
        wbt1, wbt2, wbt3, gcursor, nb, g);

    int gb = (n + 63) / 64;
    int ggb = (n + 3) / 4;

    // fused: bucket scatter (256 blocks) + layer-1 gemm (one dispatch)
    scatter_gemm1<<<NSCAT + gb, 256, 0, stream>>>(ei, E, nb, gcursor, tmp,
                                                  x, wbt1, hb, asrc, adst, n);
    bucket_sort<<<nb, 256, 0, stream>>>(tmp, gcursor, n, row_start, deg);
    int* csr = (int*)tmp;   // sorted in place

    // layer 1 aggregate
    aggregate<<<ggb, 256, 0, stream>>>(hb, asrc, adst, row_start, deg, csr, b1, xA, n);

    // layer 2
    gemm_mfma<32><<<gb, 256, 0, stream>>>(xA, wbt2, hb, asrc, adst, n);
    aggregate<<<ggb, 256, 0, stream>>>(hb, asrc, adst, row_start, deg, csr, b2, xB, n);

    // layer 3
    gemm_mfma<32><<<gb, 256, 0, stream>>>(xB, wbt3, hb, asrc, adst, n);
    aggregate<<<ggb, 256, 0, stream>>>(hb, asrc, adst, row_start, deg, csr, b3, xA, n);

    // pooling + MLP (fused; g/counter zeroed by prep_all each call)
    pool_mlp<<<256, 256, 0, stream>>>(xA, n, g, lw1, lb1, lw2, lb2, out, 1.0f / (float)n);
}